// Round 1
// 662.160 us; speedup vs baseline: 1.0525x; 1.0525x over previous
//
#include <hip/hip_runtime.h>

// GCN 3-layer forward on MI355X.
// Pipeline (A_hat (X W) = (A_hat X) W):
//   aggx:  Y1 = A_hat X         GEMM1: H1s = dinv*relu(Y1 W1 + b1)
//   agg256: Y2 = A_hat H1       GEMM2: H2 = relu(Y2 W2 + b2)
//   GEMM3: G3 = dinv*(H2 W3)    aggout: out = dinv[c]*(sum G3[r]+G3[c]) + b3 (f32)
// GEMM: m97-style LDS-tiled MFMA (128x128 tile, BK=32, global_load_lds w=16,
// ds_read_b128 frags, 4 waves x 64x64). M padded to 100096; padded rows read
// 0xAA poison (finite bf16/f32), outputs never consumed.
// CSR build: round-3-proven (atomics only on memset-initialized arrays),
// rowidx clamped at read time.
// Agg kernels (this round): multi-node-per-wave 16B/lane gathers.
//   aggx: 8 nodes/wave (8 lanes x ushort8 = 128B row), agg256: 2 nodes/wave,
//   aggout: 4 nodes/wave. Masked unroll-4 edge loop (fma-masked, tail loads
//   re-read last edge row -> L1 hit). 4KB gather bytes in flight per wave vs
//   2KB before; 2-8x fewer vmem instructions.

#define IN_F 50
#define HID  256
#define OUT_F 121
#define KP1  64      // layer-1 width padded 50->64
#define NP3  128     // layer-3 N padded 121->128
#define MPAD 100096  // 782 * 128

typedef __attribute__((ext_vector_type(8))) short bf16x8;
typedef __attribute__((ext_vector_type(4))) float f32x4;

__device__ __forceinline__ float bf2f(unsigned short u) {
    union { unsigned int i; float f; } x; x.i = ((unsigned int)u) << 16; return x.f;
}
__device__ __forceinline__ unsigned short f2bf(float f) {
    union { float f; unsigned int i; } x; x.f = f;
    unsigned int r = x.i + 0x7FFFu + ((x.i >> 16) & 1u);  // RNE
    return (unsigned short)(r >> 16);
}

__device__ __forceinline__ void gl2lds16(const void* g, void* l) {
    __builtin_amdgcn_global_load_lds(
        (const __attribute__((address_space(1))) void*)g,
        (__attribute__((address_space(3))) void*)l, 16, 0, 0);
}

// ---- edge dtype detection (int64 vs int32), 64-lane parallel ----------------
__global__ void k_detect(const int* __restrict__ ei, int* __restrict__ flag, int N) {
    int i = threadIdx.x;
    int lo = ei[2 * i], hi = ei[2 * i + 1];
    int bad = (hi != 0) || ((unsigned)lo >= (unsigned)N);
    unsigned long long m = __ballot(bad);
    if (threadIdx.x == 0) *flag = (m == 0ULL) ? 1 : 0;
}

// ---- CSR build --------------------------------------------------------------

__global__ void k_count(const int* __restrict__ ei, const int* __restrict__ flag,
                        int* __restrict__ cnt, int E, int N) {
    int t = blockIdx.x * blockDim.x + threadIdx.x;
    if (t >= E) return;
    int f = *flag;
    int c = f ? ei[2 * (E + t)] : ei[E + t];
    c = min(max(c, 0), N - 1);
    atomicAdd(&cnt[c], 1);
}

__global__ __launch_bounds__(1024) void k_scan(const int* __restrict__ cnt,
                                               int* __restrict__ offs,
                                               float* __restrict__ dinv, int n) {
    __shared__ int wsum[16];
    __shared__ int s_carry;
    int lane = threadIdx.x & 63, wid = threadIdx.x >> 6;
    if (threadIdx.x == 0) s_carry = 0;
    __syncthreads();
    for (int base = 0; base < n; base += 4096) {
        int i0 = base + (int)threadIdx.x * 4;
        int v0 = (i0 + 0 < n) ? cnt[i0 + 0] : 0;
        int v1 = (i0 + 1 < n) ? cnt[i0 + 1] : 0;
        int v2 = (i0 + 2 < n) ? cnt[i0 + 2] : 0;
        int v3 = (i0 + 3 < n) ? cnt[i0 + 3] : 0;
        int s1 = v0 + v1, s2 = s1 + v2, tsum = s2 + v3;
        int x = tsum;
        #pragma unroll
        for (int d = 1; d < 64; d <<= 1) {
            int y = __shfl_up(x, d, 64);
            if (lane >= d) x += y;
        }
        if (lane == 63) wsum[wid] = x;
        __syncthreads();
        int wpre = 0;
        #pragma unroll
        for (int j = 0; j < 16; j++) wpre += (j < wid) ? wsum[j] : 0;
        int carry = s_carry;
        int e0 = carry + wpre + x - tsum;
        if (i0 + 0 < n) { offs[i0+0]=e0;    dinv[i0+0]=rsqrtf((float)(v0+1)); }
        if (i0 + 1 < n) { offs[i0+1]=e0+v0; dinv[i0+1]=rsqrtf((float)(v1+1)); }
        if (i0 + 2 < n) { offs[i0+2]=e0+s1; dinv[i0+2]=rsqrtf((float)(v2+1)); }
        if (i0 + 3 < n) { offs[i0+3]=e0+s2; dinv[i0+3]=rsqrtf((float)(v3+1)); }
        __syncthreads();
        if (threadIdx.x == 1023) s_carry = carry + wpre + x;
        __syncthreads();
    }
    if (threadIdx.x == 0) offs[n] = s_carry;
}

__global__ void k_fill(const int* __restrict__ ei, const int* __restrict__ flag,
                       const int* __restrict__ offs,
                       int* __restrict__ fillc, int* __restrict__ rowidx, int E, int N) {
    int t = blockIdx.x * blockDim.x + threadIdx.x;
    if (t >= E) return;
    int f = *flag;
    int c = f ? ei[2 * (E + t)] : ei[E + t];
    int r = f ? ei[2 * t] : ei[t];
    c = min(max(c, 0), N - 1);
    r = min(max(r, 0), N - 1);
    int pos = offs[c] + atomicAdd(&fillc[c], 1);
    if ((unsigned)pos < (unsigned)E) rowidx[pos] = r;
}

// ---- input prep -------------------------------------------------------------

__global__ void k_padx(const float* __restrict__ x, const float* __restrict__ dinv,
                       unsigned short* __restrict__ Xs, int N) {
    int idx = blockIdx.x * blockDim.x + threadIdx.x;
    if (idx >= N * KP1) return;
    int node = idx >> 6, k = idx & 63;
    Xs[idx] = (k < IN_F) ? f2bf(dinv[node] * x[node * IN_F + k]) : (unsigned short)0;
}

__global__ void k_tr(const float* __restrict__ W, unsigned short* __restrict__ Bt,
                     int K, int Nw, int Kp, int Np) {
    int idx = blockIdx.x * blockDim.x + threadIdx.x;
    if (idx >= Np * Kp) return;
    int nn = idx / Kp, k = idx - nn * Kp;
    Bt[idx] = (k < K && nn < Nw) ? f2bf(W[k * Nw + nn]) : (unsigned short)0;
}

// ---- LDS-tiled GEMM (m97 structure) -----------------------------------------
// C[m][n] = post(sum_k A[m][k]*Bt[n][k]); A [MPAD x K], Bt [Nout x K], C [MPAD x Nout].
// Block: 256 thr = 4 waves (2x2), tile 128(M) x 128(N), BK=32. grid = (MPAD/128, Nout/128).
__global__ __launch_bounds__(256) void k_gemm_lds(const unsigned short* __restrict__ A,
                                                  const unsigned short* __restrict__ Bt,
                                                  const float* __restrict__ dinv,
                                                  const float* __restrict__ bias,
                                                  unsigned short* __restrict__ C,
                                                  int K, int Nout,
                                                  int BIAS, int RELU, int SCALE) {
    __shared__ char lds[16384];   // A tile [128][32] bf16 @0, B tile @8192
    const int tid = threadIdx.x;
    const int wid = tid >> 6, lane = tid & 63;
    const int wm = wid & 1, wn = wid >> 1;
    const int quad = lane >> 4, ml = lane & 15;
    const int m0 = blockIdx.x * 128;
    const int n0g = blockIdx.y * 128;

    f32x4 acc[4][4];
    #pragma unroll
    for (int a = 0; a < 4; a++)
        #pragma unroll
        for (int b = 0; b < 4; b++) acc[a][b] = (f32x4){0.f, 0.f, 0.f, 0.f};

    for (int kk = 0; kk < K; kk += 32) {
        #pragma unroll
        for (int r = 0; r < 2; r++) {
            int c = r * 256 + tid;            // chunk 0..511; row=c>>2, quarter=c&3
            int row = c >> 2, q = c & 3;
            gl2lds16(A  + (size_t)(m0  + row) * K + kk + q * 8, lds + c * 16);
            gl2lds16(Bt + (size_t)(n0g + row) * K + kk + q * 8, lds + 8192 + c * 16);
        }
        __syncthreads();   // drains vmcnt: LDS writes visible
        bf16x8 af[4], bfv[4];
        #pragma unroll
        for (int mf = 0; mf < 4; mf++)
            af[mf] = *(const bf16x8*)(lds + ((wm * 64 + mf * 16 + ml) * 64 + quad * 16));
        #pragma unroll
        for (int nf = 0; nf < 4; nf++)
            bfv[nf] = *(const bf16x8*)(lds + 8192 + ((wn * 64 + nf * 16 + ml) * 64 + quad * 16));
        #pragma unroll
        for (int mf = 0; mf < 4; mf++)
            #pragma unroll
            for (int nf = 0; nf < 4; nf++)
                acc[mf][nf] = __builtin_amdgcn_mfma_f32_16x16x32_bf16(af[mf], bfv[nf], acc[mf][nf], 0, 0, 0);
        __syncthreads();   // protect LDS before next stage
    }

    #pragma unroll
    for (int mf = 0; mf < 4; mf++) {
        int r0 = m0 + wm * 64 + mf * 16 + quad * 4;
        float dd[4] = {1.f, 1.f, 1.f, 1.f};
        if (SCALE) { dd[0]=dinv[r0]; dd[1]=dinv[r0+1]; dd[2]=dinv[r0+2]; dd[3]=dinv[r0+3]; }
        #pragma unroll
        for (int nf = 0; nf < 4; nf++) {
            int col = n0g + wn * 64 + nf * 16 + ml;
            float bb = BIAS ? bias[col] : 0.f;
            #pragma unroll
            for (int i = 0; i < 4; i++) {
                float v = acc[mf][nf][i] + bb;
                if (RELU) v = fmaxf(v, 0.f);
                v *= dd[i];
                C[(size_t)(r0 + i) * Nout + col] = f2bf(v);
            }
        }
    }
}

// ---- aggregation kernels ----------------------------------------------------
// Multi-node-per-wave gather: each lane loads ushort8 (16B); a wave covers
// NSUB node rows per gather instruction. Masked unroll-4 edge loop: finished
// subgroups re-load their last edge row (L1-hit) and fma-mask with 0.

__device__ __forceinline__ int rclamp(int r, int N) { return min(max(r, 0), N - 1); }

// aggx: rows 64 bf16 = 128B -> 8 lanes/row, 8 nodes/wave, 32 nodes/block.
__global__ void k_aggx(const unsigned short* __restrict__ Xs,
                       const int* __restrict__ offs, const int* __restrict__ rowidx,
                       const float* __restrict__ dinv, unsigned short* __restrict__ Y, int N) {
    int wid = threadIdx.x >> 6, lane = threadIdx.x & 63;
    int sub = lane >> 3, sl = lane & 7;
    int node = blockIdx.x * 32 + wid * 8 + sub;
    int nc = min(node, N - 1);
    int c = sl * 8;
    bf16x8 s = *(const bf16x8*)(Xs + (size_t)nc * KP1 + c);
    float a[8];
    #pragma unroll
    for (int k = 0; k < 8; k++) a[k] = bf2f((unsigned short)s[k]);
    int e = offs[nc], end = offs[nc + 1];
    if (node >= N) { e = 0; end = 0; }
    while (__any(e < end)) {
        int r[4]; float m[4];
        #pragma unroll
        for (int j = 0; j < 4; j++) {
            int idx = e + j;
            m[j] = (idx < end) ? 1.f : 0.f;
            idx = min(idx, end - 1); idx = max(idx, 0);
            r[j] = rclamp(rowidx[idx], N);
        }
        bf16x8 u[4];
        #pragma unroll
        for (int j = 0; j < 4; j++)
            u[j] = *(const bf16x8*)(Xs + (size_t)r[j] * KP1 + c);
        #pragma unroll
        for (int j = 0; j < 4; j++)
            #pragma unroll
            for (int k = 0; k < 8; k++)
                a[k] = fmaf(bf2f((unsigned short)u[j][k]), m[j], a[k]);
        e += 4;
    }
    if (node < N) {
        float dv = dinv[node];
        bf16x8 o;
        #pragma unroll
        for (int k = 0; k < 8; k++) o[k] = (short)f2bf(a[k] * dv);
        *(bf16x8*)(Y + (size_t)node * KP1 + c) = o;
    }
}

// agg256: rows 256 bf16 = 512B -> 32 lanes/row, 2 nodes/wave, 8 nodes/block.
__global__ void k_agg256(const unsigned short* __restrict__ Hn,
                         const int* __restrict__ offs, const int* __restrict__ rowidx,
                         const float* __restrict__ dinv, unsigned short* __restrict__ Y, int N) {
    int wid = threadIdx.x >> 6, lane = threadIdx.x & 63;
    int sub = lane >> 5, sl = lane & 31;
    int node = blockIdx.x * 8 + wid * 2 + sub;
    int nc = min(node, N - 1);
    int c = sl * 8;
    bf16x8 s = *(const bf16x8*)(Hn + (size_t)nc * HID + c);
    float a[8];
    #pragma unroll
    for (int k = 0; k < 8; k++) a[k] = bf2f((unsigned short)s[k]);
    int e = offs[nc], end = offs[nc + 1];
    if (node >= N) { e = 0; end = 0; }
    while (__any(e < end)) {
        int r[4]; float m[4];
        #pragma unroll
        for (int j = 0; j < 4; j++) {
            int idx = e + j;
            m[j] = (idx < end) ? 1.f : 0.f;
            idx = min(idx, end - 1); idx = max(idx, 0);
            r[j] = rclamp(rowidx[idx], N);
        }
        bf16x8 u[4];
        #pragma unroll
        for (int j = 0; j < 4; j++)
            u[j] = *(const bf16x8*)(Hn + (size_t)r[j] * HID + c);
        #pragma unroll
        for (int j = 0; j < 4; j++)
            #pragma unroll
            for (int k = 0; k < 8; k++)
                a[k] = fmaf(bf2f((unsigned short)u[j][k]), m[j], a[k]);
        e += 4;
    }
    if (node < N) {
        float dv = dinv[node];
        bf16x8 o;
        #pragma unroll
        for (int k = 0; k < 8; k++) o[k] = (short)f2bf(a[k] * dv);
        *(bf16x8*)(Y + (size_t)node * HID + c) = o;
    }
}

// aggout: rows 128 bf16 = 256B -> 16 lanes/row, 4 nodes/wave, 16 nodes/block.
__global__ void k_aggout(const unsigned short* __restrict__ G,
                         const int* __restrict__ offs, const int* __restrict__ rowidx,
                         const float* __restrict__ dinv, const float* __restrict__ bias,
                         float* __restrict__ out, int N) {
    int wid = threadIdx.x >> 6, lane = threadIdx.x & 63;
    int sub = lane >> 4, sl = lane & 15;
    int node = blockIdx.x * 16 + wid * 4 + sub;
    int nc = min(node, N - 1);
    int c = sl * 8;
    bf16x8 s = *(const bf16x8*)(G + (size_t)nc * NP3 + c);
    float a[8];
    #pragma unroll
    for (int k = 0; k < 8; k++) a[k] = bf2f((unsigned short)s[k]);
    int e = offs[nc], end = offs[nc + 1];
    if (node >= N) { e = 0; end = 0; }
    while (__any(e < end)) {
        int r[4]; float m[4];
        #pragma unroll
        for (int j = 0; j < 4; j++) {
            int idx = e + j;
            m[j] = (idx < end) ? 1.f : 0.f;
            idx = min(idx, end - 1); idx = max(idx, 0);
            r[j] = rclamp(rowidx[idx], N);
        }
        bf16x8 u[4];
        #pragma unroll
        for (int j = 0; j < 4; j++)
            u[j] = *(const bf16x8*)(G + (size_t)r[j] * NP3 + c);
        #pragma unroll
        for (int j = 0; j < 4; j++)
            #pragma unroll
            for (int k = 0; k < 8; k++)
                a[k] = fmaf(bf2f((unsigned short)u[j][k]), m[j], a[k]);
        e += 4;
    }
    if (node < N) {
        float dv = dinv[node];
        #pragma unroll
        for (int k = 0; k < 8; k++) {
            int col = c + k;
            if (col < OUT_F)
                out[(size_t)node * OUT_F + col] = fmaf(a[k], dv, bias[col]);
        }
    }
}

// ---- launch -----------------------------------------------------------------

extern "C" void kernel_launch(void* const* d_in, const int* in_sizes, int n_in,
                              void* d_out, int out_size, void* d_ws, size_t ws_size,
                              hipStream_t stream) {
    const float* x  = (const float*)d_in[0];
    const int*   ei = (const int*)d_in[1];
    const float* W1 = (const float*)d_in[2];
    const float* b1 = (const float*)d_in[3];
    const float* W2 = (const float*)d_in[4];
    const float* b2 = (const float*)d_in[5];
    const float* W3 = (const float*)d_in[6];
    const float* b3 = (const float*)d_in[7];
    float* out = (float*)d_out;

    const int N = in_sizes[0] / IN_F;     // 100000
    const int E = in_sizes[1] / 2;        // 1600000

    char* w = (char*)d_ws;
    size_t off = 0;
    auto alloc = [&](size_t bytes) -> char* {
        char* p = w + off;
        off += (bytes + 255) & ~(size_t)255;
        return p;
    };
    int*   cnt    = (int*)  alloc((size_t)N * 4);
    int*   offs   = (int*)  alloc((size_t)(N + 1) * 4);
    int*   fillc  = (int*)  alloc((size_t)N * 4);
    float* dinv   = (float*)alloc((size_t)MPAD * 4);   // padded: GEMM epilogue reads r<MPAD
    int*   flag   = (int*)  alloc(256);
    int*   rowidx = (int*)  alloc((size_t)E * 4);
    unsigned short* Bt1 = (unsigned short*)alloc((size_t)HID * KP1 * 2);
    unsigned short* Bt2 = (unsigned short*)alloc((size_t)HID * HID * 2);
    unsigned short* Bt3 = (unsigned short*)alloc((size_t)NP3 * HID * 2);
    unsigned short* bufA = (unsigned short*)alloc((size_t)MPAD * HID * 2);  // Xs -> H1s -> H2
    unsigned short* bufB = (unsigned short*)alloc((size_t)MPAD * HID * 2);  // Y1 -> Y2 -> G3
    unsigned short* Xs  = bufA;
    unsigned short* Y1  = bufB;
    unsigned short* H1s = bufA;
    unsigned short* Y2  = bufB;
    unsigned short* H2  = bufA;
    unsigned short* G3  = bufB;

    hipMemsetAsync(cnt, 0, (size_t)N * 4, stream);
    hipMemsetAsync(fillc, 0, (size_t)N * 4, stream);
    hipMemsetAsync(rowidx, 0, (size_t)E * 4, stream);

    k_detect<<<1, 64, 0, stream>>>(ei, flag, N);
    k_count<<<(E + 255) / 256, 256, 0, stream>>>(ei, flag, cnt, E, N);
    k_scan<<<1, 1024, 0, stream>>>(cnt, offs, dinv, N);
    k_fill<<<(E + 255) / 256, 256, 0, stream>>>(ei, flag, offs, fillc, rowidx, E, N);

    k_padx<<<(N * KP1 + 255) / 256, 256, 0, stream>>>(x, dinv, Xs, N);
    k_tr<<<(HID * KP1 + 255) / 256, 256, 0, stream>>>(W1, Bt1, IN_F, HID, KP1, HID);
    k_tr<<<(HID * HID + 255) / 256, 256, 0, stream>>>(W2, Bt2, HID, HID, HID, HID);
    k_tr<<<(NP3 * HID + 255) / 256, 256, 0, stream>>>(W3, Bt3, HID, OUT_F, HID, NP3);

    dim3 g12(MPAD / 128, HID / 128);   // (782, 2)
    dim3 g3(MPAD / 128, NP3 / 128);    // (782, 1)

    // layer 1: aggregate-first, then GEMM (+b1, relu, *dinv)
    k_aggx<<<(N + 31) / 32, 256, 0, stream>>>(Xs, offs, rowidx, dinv, Y1, N);
    k_gemm_lds<<<g12, 256, 0, stream>>>(Y1, Bt1, dinv, b1, H1s, KP1, HID, 1, 1, 1);
    // layer 2: aggregate H1s, then GEMM (+b2, relu)
    k_agg256<<<(N + 7) / 8, 256, 0, stream>>>(H1s, offs, rowidx, dinv, Y2, N);
    k_gemm_lds<<<g12, 256, 0, stream>>>(Y2, Bt2, dinv, b2, H2, HID, HID, 1, 1, 0);
    // layer 3: GEMM (*dinv), then aggregate (+b3), f32 out
    k_gemm_lds<<<g3, 256, 0, stream>>>(H2, Bt3, dinv, b3, G3, HID, NP3, 0, 0, 1);
    k_aggout<<<(N + 15) / 16, 256, 0, stream>>>(G3, offs, rowidx, dinv, b3, out, N);

    (void)n_in; (void)out_size; (void)ws_size;
}